// Round 10
// baseline (343.191 us; speedup 1.0000x reference)
//
#include <hip/hip_runtime.h>
#include <hip/hip_cooperative_groups.h>
#include <hip/hip_bf16.h>
#include <float.h>

namespace cg = cooperative_groups;

// Problem constants (B=1)
#define HWQ   1024
#define NK    40960
#define NCH   64
#define NTOP  10
#define CAPS  64                  // per-(query,shard) candidate cap (E~21, P(ovf)~7e-13)
#define R2    144                 // circle radius^2 (radius 12, strict <)
#define TOTU  23556               // 39 frames x 604 row-units
#define NWAVE 2048                // 512 blocks x 4 waves
#define TSCALE 14.2857142857142857f
#define LOSCL  4.8828125e-4f      // 1/2048

typedef _Float16 f16x8 __attribute__((ext_vector_type(8)));
typedef float    f32x4 __attribute__((ext_vector_type(4)));
typedef unsigned short us8 __attribute__((ext_vector_type(8)));
typedef unsigned long long u64;
typedef unsigned int       u32;

__device__ inline float bf16bits_to_f32(unsigned short u) {
    union { u32 i; float f; } z; z.i = ((u32)u) << 16; return z.f;
}
__device__ inline unsigned short f32_to_bf16bits(float x) {
    __hip_bfloat16 b = __float2bfloat16(x);
    return *(unsigned short*)&b;
}

// ---- dtype self-sniff (bf16 vs fp32 inputs), wave-uniform ----------------
__device__ inline int sniff_fp32(const unsigned short* __restrict__ raw) {
    const int lane = threadIdx.x & 63;
    const int e = (raw[lane] >> 7) & 0xFF;
    const u64 m = __ballot(e < 100 || e > 133);
    return __popcll(m) > 16;
}

// ---- ordered-float pack: ordered-f32 << 16 | ~idx (lower idx wins ties) --
__device__ inline u32 ord32(float v) {
    const u32 b = __float_as_uint(v);
    return b ^ (u32)(((int)b >> 31) | (int)0x80000000);
}
__device__ inline u64 pack_vi(float val, int kidx) {
    return ((u64)ord32(val) << 16) | (u32)(0xFFFF - kidx);
}
__device__ inline float unpack_val(u64 p) {
    const u32 u = (u32)(p >> 16);
    const u32 b = u ^ (~((u32)((int)u >> 31)) | 0x80000000u);
    return __uint_as_float(b);
}
__device__ inline int unpack_idx(u64 p) { return 0xFFFF - (int)(p & 0xFFFF); }

// ---- branchless shift-insert into descending sorted v[10] ----------------
__device__ inline void ins10(u64* v, u64 pk) {
#pragma unroll
    for (int j = NTOP - 1; j >= 1; --j) {
        const bool gj = pk > v[j];
        const bool gp = pk > v[j - 1];
        v[j] = gj ? (gp ? v[j - 1] : pk) : v[j];
    }
    if (pk > v[0]) v[0] = pk;
}

// ---- merge 4 sorted 10-lists laid out base[p*160 + lane*10 + j] ----------
__device__ inline void merge4(const u64* base, int lane, u64* out10) {
    int p0 = 0, p1 = 0, p2 = 0, p3 = 0;
    const u64* b = base + lane * 10;
#pragma unroll
    for (int r = 0; r < NTOP; ++r) {
        const u64 h0 = b[p0], h1 = b[160 + p1], h2 = b[320 + p2], h3 = b[480 + p3];
        u64 m = h0; int sel = 0;
        if (h1 > m) { m = h1; sel = 1; }
        if (h2 > m) { m = h2; sel = 2; }
        if (h3 > m) { m = h3; sel = 3; }
        out10[r] = m;
        p0 += (sel == 0); p1 += (sel == 1); p2 += (sel == 2); p3 += (sel == 3);
    }
}

// ---- sharded candidate flush (128B-stride counters: lane owns a line) ----
__device__ inline void flush_cand(int* cnt, u64* gcand, int q, int shard, u64 pk) {
    const int pos = atomicAdd(&cnt[q * 32 + shard], 1);
    if (pos < CAPS) gcand[((size_t)q * 8 + shard) * CAPS + pos] = pk;
}

// ===================== the single cooperative kernel ======================
__global__ __launch_bounds__(256, 2) void fused_kernel(
    const void* __restrict__ qin_, const void* __restrict__ kin_,
    const void* __restrict__ vin_,
    f16x8* __restrict__ kh, f16x8* __restrict__ kl,
    f16x8* __restrict__ qh, f16x8* __restrict__ ql,
    unsigned short* __restrict__ vt,
    u64* __restrict__ pv, float* __restrict__ thmax,
    u64* __restrict__ gcand, int* __restrict__ cnt,
    void* __restrict__ out_)
{
    __shared__ __align__(16) char shraw[25600];
    cg::grid_group grid = cg::this_grid();

    const int bid  = blockIdx.x;
    const int tid  = threadIdx.x;
    const int w    = tid >> 6;
    const int lane = tid & 63;
    const int quad = lane >> 4;
    const int n    = lane & 15;
    const int isf  = sniff_fp32((const unsigned short*)kin_);

    // ---------------- Phase A: prep (K,V,Q) + zero counters ---------------
    {
        const int zi = bid * 256 + tid;          // 131072 threads = 1024*32*4B ints... (32768 ints)
        if (zi < 32768) cnt[zi] = 0;

        float (*ssq)[64] = (float(*)[64])shraw;
        const int c0 = w * 16;
        for (int u = bid; u < 656; u += 512) {
            if (u < 640) {
                const int key = u * 64 + lane;
                float x[16];
                if (isf) {
                    const float* p = (const float*)kin_;
#pragma unroll
                    for (int i = 0; i < 16; ++i) x[i] = p[(c0 + i) * NK + key];
                } else {
                    const __hip_bfloat16* p = (const __hip_bfloat16*)kin_;
#pragma unroll
                    for (int i = 0; i < 16; ++i) x[i] = __bfloat162float(p[(c0 + i) * NK + key]);
                }
                float s = 0.f;
#pragma unroll
                for (int i = 0; i < 16; ++i) s = fmaf(x[i], x[i], s);
                ssq[w][lane] = s;
                __syncthreads();
                s = ssq[0][lane] + ssq[1][lane] + ssq[2][lane] + ssq[3][lane];
                const float rn = 1.0f / fmaxf(sqrtf(s), 1e-12f);

                const int tb = (key >> 4) * 128 + (key & 15);
#pragma unroll
                for (int b2 = 0; b2 < 2; ++b2) {
                    f16x8 h, l;
#pragma unroll
                    for (int jj = 0; jj < 8; ++jj) {
                        const float xv = x[b2 * 8 + jj] * rn;
                        const _Float16 hh = (_Float16)xv;
                        h[jj] = hh;
                        l[jj] = (_Float16)((xv - (float)hh) * 2048.0f);  // scaled lo stays normal
                    }
                    kh[tb + (w * 2 + b2) * 16] = h;
                    kl[tb + (w * 2 + b2) * 16] = l;
                }

                unsigned short vv[16];
                if (isf) {
                    const float* p = (const float*)vin_;
#pragma unroll
                    for (int i = 0; i < 16; ++i) vv[i] = f32_to_bf16bits(p[(c0 + i) * NK + key]);
                } else {
                    const unsigned short* p = (const unsigned short*)vin_;
#pragma unroll
                    for (int i = 0; i < 16; ++i) vv[i] = p[(c0 + i) * NK + key];
                }
                us8* dst = (us8*)(vt + (size_t)key * NCH + c0);
#pragma unroll
                for (int b2 = 0; b2 < 2; ++b2) {
                    us8 o;
#pragma unroll
                    for (int e = 0; e < 8; ++e) o[e] = vv[b2 * 8 + e];
                    dst[b2] = o;
                }
                __syncthreads();   // protect ssq reuse
            } else {
                const int q = (u - 640) * 64 + lane;
                float x[16];
                if (isf) {
                    const float* p = (const float*)qin_;
#pragma unroll
                    for (int i = 0; i < 16; ++i) x[i] = p[(c0 + i) * HWQ + q];
                } else {
                    const __hip_bfloat16* p = (const __hip_bfloat16*)qin_;
#pragma unroll
                    for (int i = 0; i < 16; ++i) x[i] = __bfloat162float(p[(c0 + i) * HWQ + q]);
                }
                float s = 0.f;
#pragma unroll
                for (int i = 0; i < 16; ++i) s = fmaf(x[i], x[i], s);
                ssq[w][lane] = s;
                __syncthreads();
                s = ssq[0][lane] + ssq[1][lane] + ssq[2][lane] + ssq[3][lane];
                const float rn = 1.0f / fmaxf(sqrtf(s), 1e-12f);  // 1/TEMP in finalize

                const int tb = (q >> 4) * 128 + (q & 15);
#pragma unroll
                for (int b2 = 0; b2 < 2; ++b2) {
                    f16x8 h, l;
#pragma unroll
                    for (int jj = 0; jj < 8; ++jj) {
                        const float xv = x[b2 * 8 + jj] * rn;
                        const _Float16 hh = (_Float16)xv;
                        h[jj] = hh;
                        l[jj] = (_Float16)((xv - (float)hh) * 2048.0f);
                    }
                    qh[tb + (w * 2 + b2) * 16] = h;
                    ql[tb + (w * 2 + b2) * 16] = l;
                }
                __syncthreads();
            }
        }
    }

    grid.sync();

    // ---------------- Phase B: frame-0 exact top-10 + theta ---------------
    // Blocks 0..63: block = qtile t (16 queries). Wave w: tiles w*16..+16.
    {
        u64* smb = (u64*)shraw;              // [4 waves][4 quads][16 n][10]
        u64* wmb = (u64*)(shraw + 20480);    // [4 waves][16 n][10]

        if (bid < 64) {
            const int t = bid;
            const int qb = t * 128 + n;
            const f16x8 bh0 = qh[qb + quad * 16];
            const f16x8 bh1 = qh[qb + (4 + quad) * 16];
            const f16x8 bl0 = ql[qb + quad * 16];
            const f16x8 bl1 = ql[qb + (4 + quad) * 16];

            u64 v[NTOP];
#pragma unroll
            for (int jj = 0; jj < NTOP; ++jj) v[jj] = 0ull;

            const int start = w * 16, end = start + 16;
            const int loff = (n + quad * 16) * 16;
            const char* ph = (const char*)kh + (size_t)start * 2048 + loff;
            const char* pl = (const char*)kl + (size_t)start * 2048 + loff;

            for (int kt = start; kt < end; ++kt) {
                const f16x8 Ah0 = *(const f16x8*)(ph);
                const f16x8 Ah1 = *(const f16x8*)(ph + 1024);
                const f16x8 Al0 = *(const f16x8*)(pl);
                const f16x8 Al1 = *(const f16x8*)(pl + 1024);

                f32x4 aH = {0.f,0.f,0.f,0.f}, aL0 = {0.f,0.f,0.f,0.f}, aL1 = {0.f,0.f,0.f,0.f};
                aH  = __builtin_amdgcn_mfma_f32_16x16x32_f16(Ah0, bh0, aH, 0, 0, 0);
                aH  = __builtin_amdgcn_mfma_f32_16x16x32_f16(Ah1, bh1, aH, 0, 0, 0);
                aL0 = __builtin_amdgcn_mfma_f32_16x16x32_f16(Ah0, bl0, aL0, 0, 0, 0);
                aL0 = __builtin_amdgcn_mfma_f32_16x16x32_f16(Al0, bh0, aL0, 0, 0, 0);
                aL1 = __builtin_amdgcn_mfma_f32_16x16x32_f16(Ah1, bl1, aL1, 0, 0, 0);
                aL1 = __builtin_amdgcn_mfma_f32_16x16x32_f16(Al1, bh1, aL1, 0, 0, 0);

                const int key0 = kt * 16 + quad * 4;
#pragma unroll
                for (int r = 0; r < 4; ++r) {
                    const float val = fmaf(aL0[r] + aL1[r], LOSCL, aH[r]);
                    const u64 pk = pack_vi(val, key0 + r);
                    if (pk > v[NTOP - 1]) ins10(v, pk);
                }
                ph += 2048; pl += 2048;
            }

            // wave-internal quad merge (DS ops ordered by lgkmcnt, no barrier)
#pragma unroll
            for (int jj = 0; jj < NTOP; ++jj)
                smb[(size_t)w * 640 + (quad * 16 + n) * 10 + jj] = v[jj];
            if (lane < 16) {
                u64 o10[NTOP];
                merge4(smb + (size_t)w * 640, lane, o10);
#pragma unroll
                for (int r = 0; r < NTOP; ++r) wmb[(size_t)w * 160 + lane * 10 + r] = o10[r];
            }
        }
        __syncthreads();   // all 4 waves of every block (idle blocks sync trivially)
        if (bid < 64 && tid < 16) {
            u64 o10[NTOP];
            merge4(wmb, tid, o10);     // cross-wave merge -> true frame-0 top-10
            const int q = bid * 16 + tid;
#pragma unroll
            for (int r = 0; r < NTOP; ++r) pv[(size_t)q * NTOP + r] = o10[r];
            thmax[q] = unpack_val(o10[9]);
        }
    }

    grid.sync();

    // ---------------- Phase C: masked frames (flat row-units) -------------
    {
        const int wid = ((bid & 7) * 64 + (bid >> 3)) * 4 + w;   // XCD-contiguous
        const int u0  = (int)(((long long)wid * TOTU) >> 11);
        const int u1  = (int)(((long long)(wid + 1) * TOTU) >> 11);

        f16x8 b0h0, b0h1, b0l0, b0l1, b1h0, b1h1, b1l0, b1l1;
        float theta0 = 0.f, theta1 = 0.f;
        int cur_qy = -1, q0 = 0;

        for (int u = u0; u < u1; ++u) {
            // decode u -> (frame, qy, row); wave-uniform
            const int fm1 = u / 604;
            const int rem = u - fm1 * 604;
            int qy, off;
            if (rem < 210) {
                int t = (int)((sqrtf((float)(529 + 8 * rem)) - 23.0f) * 0.5f);
                while ((t * (t + 23)) / 2 > rem) --t;
                while (((t + 1) * (t + 24)) / 2 <= rem) ++t;
                qy = t; off = rem - (t * (t + 23)) / 2;
            } else if (rem < 417) {
                qy = 12 + (rem - 210) / 23; off = (rem - 210) % 23;
            } else {
                const int s = 603 - rem;
                int t = (int)((sqrtf((float)(529 + 8 * s)) - 23.0f) * 0.5f);
                while ((t * (t + 23)) / 2 > s) --t;
                while (((t + 1) * (t + 24)) / 2 <= s) ++t;
                qy = 31 - t;
                off = (12 + t) - 1 - (s - (t * (t + 23)) / 2);
            }
            const int rlo = (qy > 11) ? qy - 11 : 0;
            const int row = rlo + off;
            const int frame = fm1 + 1;
            const int shard = fm1 / 5;                 // 8 shards (frame chunks)

            if (qy != cur_qy) {
                cur_qy = qy;
                const int qb = qy * 256 + n;
                b0h0 = qh[qb + quad * 16];       b0h1 = qh[qb + (4 + quad) * 16];
                b0l0 = ql[qb + quad * 16];       b0l1 = ql[qb + (4 + quad) * 16];
                b1h0 = qh[qb + 128 + quad * 16]; b1h1 = qh[qb + 128 + (4 + quad) * 16];
                b1l0 = ql[qb + 128 + quad * 16]; b1l1 = ql[qb + 128 + (4 + quad) * 16];
                q0 = qy * 32 + n;
                theta0 = thmax[q0];
                theta1 = thmax[q0 + 16];
            }

            const int dy    = row - qy;
            const int rem2  = R2 - dy * dy;
            const int tbase = frame * 64 + row * 2;
            const int keyrow = frame * 1024 + row * 32;

            u64 s0 = 0ull, s1 = 0ull;   // per-lane 1-slot buffers (q0 / q0+16)

#pragma unroll 1
            for (int kt2 = 0; kt2 < 2; ++kt2) {
                const f16x8* pA = kh + (tbase + kt2) * 128 + n;
                const f16x8* pL = kl + (tbase + kt2) * 128 + n;
                const f16x8 ah0 = pA[quad * 16];
                const f16x8 ah1 = pA[(4 + quad) * 16];
                const f16x8 al0 = pL[quad * 16];
                const f16x8 al1 = pL[(4 + quad) * 16];

                f32x4 H0 = {0.f,0.f,0.f,0.f}, L00 = {0.f,0.f,0.f,0.f}, L01 = {0.f,0.f,0.f,0.f};
                f32x4 H1 = {0.f,0.f,0.f,0.f}, L10 = {0.f,0.f,0.f,0.f}, L11 = {0.f,0.f,0.f,0.f};
                H0  = __builtin_amdgcn_mfma_f32_16x16x32_f16(ah0, b0h0, H0, 0, 0, 0);
                H0  = __builtin_amdgcn_mfma_f32_16x16x32_f16(ah1, b0h1, H0, 0, 0, 0);
                L00 = __builtin_amdgcn_mfma_f32_16x16x32_f16(ah0, b0l0, L00, 0, 0, 0);
                L00 = __builtin_amdgcn_mfma_f32_16x16x32_f16(al0, b0h0, L00, 0, 0, 0);
                L01 = __builtin_amdgcn_mfma_f32_16x16x32_f16(ah1, b0l1, L01, 0, 0, 0);
                L01 = __builtin_amdgcn_mfma_f32_16x16x32_f16(al1, b0h1, L01, 0, 0, 0);
                H1  = __builtin_amdgcn_mfma_f32_16x16x32_f16(ah0, b1h0, H1, 0, 0, 0);
                H1  = __builtin_amdgcn_mfma_f32_16x16x32_f16(ah1, b1h1, H1, 0, 0, 0);
                L10 = __builtin_amdgcn_mfma_f32_16x16x32_f16(ah0, b1l0, L10, 0, 0, 0);
                L10 = __builtin_amdgcn_mfma_f32_16x16x32_f16(al0, b1h0, L10, 0, 0, 0);
                L11 = __builtin_amdgcn_mfma_f32_16x16x32_f16(ah1, b1l1, L11, 0, 0, 0);
                L11 = __builtin_amdgcn_mfma_f32_16x16x32_f16(al1, b1h1, L11, 0, 0, 0);

                const int kx0  = kt2 * 16 + quad * 4;
                const int key0 = keyrow + kx0;
#pragma unroll
                for (int r = 0; r < 4; ++r) {
                    const float v0 = fmaf(L00[r] + L01[r], LOSCL, H0[r]);
                    const float v1 = fmaf(L10[r] + L11[r], LOSCL, H1[r]);
                    if (v0 > theta0) {                        // rare (~0.5%)
                        const int dx = kx0 + r - n;
                        if (dx * dx < rem2) {
                            if (s0) flush_cand(cnt, gcand, q0, shard, s0);  // collision: rare^2
                            s0 = pack_vi(v0, key0 + r);
                        }
                    }
                    if (v1 > theta1) {
                        const int dx = kx0 + r - 16 - n;
                        if (dx * dx < rem2) {
                            if (s1) flush_cand(cnt, gcand, q0 + 16, shard, s1);
                            s1 = pack_vi(v1, key0 + r);
                        }
                    }
                }
            }
            if (s0) flush_cand(cnt, gcand, q0, shard, s0);
            if (s1) flush_cand(cnt, gcand, q0 + 16, shard, s1);
        }
    }

    grid.sync();

    // ---------------- Phase D: merge, softmax, gather, write --------------
    {
        const int q = bid * 4 + w;
        if (q < HWQ) {
            u64 lv[9];
            lv[0] = (lane < NTOP) ? pv[(size_t)q * NTOP + lane] : 0ull;
#pragma unroll
            for (int e = 0; e < 8; ++e) {
                const int c = cnt[q * 32 + e];
                const int cc = c < CAPS ? c : CAPS;
                lv[1 + e] = (lane < cc) ? gcand[((size_t)q * 8 + e) * CAPS + lane] : 0ull;
            }

            float wv[NTOP]; int wi[NTOP];
#pragma unroll
            for (int r = 0; r < NTOP; ++r) {
                u64 m = lv[0];
#pragma unroll
                for (int e = 1; e < 9; ++e) if (lv[e] > m) m = lv[e];
#pragma unroll
                for (int off = 32; off >= 1; off >>= 1) {     // wave64 max on u64
                    const u32 lo = (u32)m, hi = (u32)(m >> 32);
                    const u32 lo2 = (u32)__shfl_xor((int)lo, off);
                    const u32 hi2 = (u32)__shfl_xor((int)hi, off);
                    const u64 o = ((u64)hi2 << 32) | lo2;
                    if (o > m) m = o;
                }
#pragma unroll
                for (int e = 0; e < 9; ++e) if (lv[e] == m) lv[e] = 0ull;   // consume
                wv[r] = unpack_val(m); wi[r] = unpack_idx(m);
            }

            float ww[NTOP]; float wsum = 0.f;
#pragma unroll
            for (int r = 0; r < NTOP; ++r) { ww[r] = expf((wv[r] - wv[0]) * TSCALE); wsum += ww[r]; }
            const float inv = 1.0f / wsum;

            float acc = 0.f;
#pragma unroll
            for (int r = 0; r < NTOP; ++r)
                acc += ww[r] * bf16bits_to_f32(vt[(size_t)wi[r] * NCH + lane]);
            const float res = acc * inv;

            if (isf) ((float*)out_)[lane * HWQ + q] = res;
            else     ((__hip_bfloat16*)out_)[lane * HWQ + q] = __float2bfloat16(res);
        }
    }
}

// ---------------- launcher ------------------------------------------------
extern "C" void kernel_launch(void* const* d_in, const int* in_sizes, int n_in,
                              void* d_out, int out_size, void* d_ws, size_t ws_size,
                              hipStream_t stream)
{
    const void* qin = d_in[0];   // (64,1024)   bf16 or fp32 (self-sniffed)
    const void* kin = d_in[1];   // (64,40960)
    const void* vin = d_in[2];   // (64,40960)
    // d_in[3] (mask) recomputed on device.

    char* wsp = (char*)d_ws;
    f16x8*          kh    = (f16x8*)(wsp);                     //  5,242,880 B
    f16x8*          kl    = (f16x8*)(wsp + 5242880);           //  5,242,880 B
    f16x8*          qhv   = (f16x8*)(wsp + 10485760);          //    131,072 B
    f16x8*          qlv   = (f16x8*)(wsp + 10616832);          //    131,072 B
    unsigned short* vt    = (unsigned short*)(wsp + 10747904); //  5,242,880 B
    u64*            pv    = (u64*)(wsp + 15990784);            //     81,920 B
    float*          thmax = (float*)(wsp + 16072704);          //      4,096 B
    u64*            gcand = (u64*)(wsp + 16076800);            //  4,194,304 B
    int*            cnt   = (int*)(wsp + 20271104);            //    131,072 B

    void* out = d_out;
    void* args[] = {
        (void*)&qin, (void*)&kin, (void*)&vin,
        (void*)&kh, (void*)&kl, (void*)&qhv, (void*)&qlv,
        (void*)&vt, (void*)&pv, (void*)&thmax,
        (void*)&gcand, (void*)&cnt, (void*)&out
    };
    hipLaunchCooperativeKernel((const void*)fused_kernel,
                               dim3(512), dim3(256), args, 0, stream);
}

// Round 11
// 120.968 us; speedup vs baseline: 2.8370x; 2.8370x over previous
//
#include <hip/hip_runtime.h>
#include <hip/hip_bf16.h>
#include <float.h>

// Problem constants (B=1)
#define HWQ   1024
#define NK    40960
#define NCH   64
#define NTOP  10
#define NF0JOB 8
#define PVLEN (NF0JOB * NTOP)     // 80 frame-0 entries per query
#define CAPG  384                 // global candidate cap per query (E~168, >12 sigma)
#define CAPW  16                  // per-wave per-query LDS cap (E~1.4, P(ovf)~1e-13)
#define R2    144                 // circle radius^2 (radius 12, strict <)
#define TOTU  23556               // 39 frames x 604 row-units
#define NBLK  1024                // masked grid: 1024 blocks x 4 independent waves
#define TSCALE 14.2857142857142857f
#define LOSCL  4.8828125e-4f      // 1/2048

typedef _Float16 f16x8 __attribute__((ext_vector_type(8)));
typedef float    f32x4 __attribute__((ext_vector_type(4)));
typedef unsigned short us8 __attribute__((ext_vector_type(8)));
typedef unsigned long long u64;
typedef unsigned int       u32;

__device__ inline float bf16bits_to_f32(unsigned short u) {
    union { u32 i; float f; } z; z.i = ((u32)u) << 16; return z.f;
}
__device__ inline unsigned short f32_to_bf16bits(float x) {
    __hip_bfloat16 b = __float2bfloat16(x);
    return *(unsigned short*)&b;
}

// ---- dtype self-sniff (bf16 vs fp32 inputs), wave-uniform ----------------
__device__ inline int sniff_fp32(const unsigned short* __restrict__ raw) {
    const int lane = threadIdx.x & 63;
    const int e = (raw[lane] >> 7) & 0xFF;
    const u64 m = __ballot(e < 100 || e > 133);
    return __popcll(m) > 16;
}

// ---- ordered-float pack: ordered-f32 << 16 | ~idx (lower idx wins ties) --
__device__ inline u32 ord32(float v) {
    const u32 b = __float_as_uint(v);
    return b ^ (u32)(((int)b >> 31) | (int)0x80000000);
}
__device__ inline u64 pack_vi(float val, int kidx) {
    return ((u64)ord32(val) << 16) | (u32)(0xFFFF - kidx);
}
__device__ inline float unpack_val(u64 p) {
    const u32 u = (u32)(p >> 16);
    const u32 b = u ^ (~((u32)((int)u >> 31)) | 0x80000000u);
    return __uint_as_float(b);
}
__device__ inline int unpack_idx(u64 p) { return 0xFFFF - (int)(p & 0xFFFF); }

// ---- branchless shift-insert into descending sorted v[10] ----------------
__device__ inline void ins10(u64* v, u64 pk) {
#pragma unroll
    for (int j = NTOP - 1; j >= 1; --j) {
        const bool gj = pk > v[j];
        const bool gp = pk > v[j - 1];
        v[j] = gj ? (gp ? v[j - 1] : pk) : v[j];
    }
    if (pk > v[0]) v[0] = pk;
}

// ---------------- kernel 1: prep (coalesced), 256 thr = 4 waves -----------
__global__ __launch_bounds__(256) void prep_all(
    const void* __restrict__ qin_, const void* __restrict__ kin_,
    const void* __restrict__ vin_,
    f16x8* __restrict__ kh, f16x8* __restrict__ kl,
    f16x8* __restrict__ qh, f16x8* __restrict__ ql,
    unsigned short* __restrict__ vt, int* __restrict__ cnt)
{
    __shared__ float ssq[4][64];
    const int isf  = sniff_fp32((const unsigned short*)kin_);
    const int bid  = blockIdx.x;
    const int tid  = threadIdx.x;
    const int w    = tid >> 6;
    const int lane = tid & 63;
    const int c0   = w * 16;

    if (bid == 655) {
        cnt[tid * 4 + 0] = 0; cnt[tid * 4 + 1] = 0;
        cnt[tid * 4 + 2] = 0; cnt[tid * 4 + 3] = 0;
    }

    if (bid < 640) {
        const int key = bid * 64 + lane;
        float x[16];
        if (isf) {
            const float* p = (const float*)kin_;
#pragma unroll
            for (int i = 0; i < 16; ++i) x[i] = p[(c0 + i) * NK + key];
        } else {
            const __hip_bfloat16* p = (const __hip_bfloat16*)kin_;
#pragma unroll
            for (int i = 0; i < 16; ++i) x[i] = __bfloat162float(p[(c0 + i) * NK + key]);
        }
        float s = 0.f;
#pragma unroll
        for (int i = 0; i < 16; ++i) s = fmaf(x[i], x[i], s);
        ssq[w][lane] = s;
        __syncthreads();
        s = ssq[0][lane] + ssq[1][lane] + ssq[2][lane] + ssq[3][lane];
        const float rn = 1.0f / fmaxf(sqrtf(s), 1e-12f);

        const int tb = (key >> 4) * 128 + (key & 15);
#pragma unroll
        for (int b2 = 0; b2 < 2; ++b2) {
            f16x8 h, l;
#pragma unroll
            for (int jj = 0; jj < 8; ++jj) {
                const float xv = x[b2 * 8 + jj] * rn;
                const _Float16 hh = (_Float16)xv;
                h[jj] = hh;
                l[jj] = (_Float16)((xv - (float)hh) * 2048.0f);  // scaled lo stays normal
            }
            kh[tb + (w * 2 + b2) * 16] = h;
            kl[tb + (w * 2 + b2) * 16] = l;
        }

        unsigned short vv[16];
        if (isf) {
            const float* p = (const float*)vin_;
#pragma unroll
            for (int i = 0; i < 16; ++i) vv[i] = f32_to_bf16bits(p[(c0 + i) * NK + key]);
        } else {
            const unsigned short* p = (const unsigned short*)vin_;
#pragma unroll
            for (int i = 0; i < 16; ++i) vv[i] = p[(c0 + i) * NK + key];
        }
        us8* dst = (us8*)(vt + (size_t)key * NCH + c0);
#pragma unroll
        for (int b2 = 0; b2 < 2; ++b2) {
            us8 o;
#pragma unroll
            for (int e = 0; e < 8; ++e) o[e] = vv[b2 * 8 + e];
            dst[b2] = o;
        }
    } else {
        const int q = (bid - 640) * 64 + lane;
        float x[16];
        if (isf) {
            const float* p = (const float*)qin_;
#pragma unroll
            for (int i = 0; i < 16; ++i) x[i] = p[(c0 + i) * HWQ + q];
        } else {
            const __hip_bfloat16* p = (const __hip_bfloat16*)qin_;
#pragma unroll
            for (int i = 0; i < 16; ++i) x[i] = __bfloat162float(p[(c0 + i) * HWQ + q]);
        }
        float s = 0.f;
#pragma unroll
        for (int i = 0; i < 16; ++i) s = fmaf(x[i], x[i], s);
        ssq[w][lane] = s;
        __syncthreads();
        s = ssq[0][lane] + ssq[1][lane] + ssq[2][lane] + ssq[3][lane];
        const float rn = 1.0f / fmaxf(sqrtf(s), 1e-12f);   // 1/TEMP applied in finalize

        const int tb = (q >> 4) * 128 + (q & 15);
#pragma unroll
        for (int b2 = 0; b2 < 2; ++b2) {
            f16x8 h, l;
#pragma unroll
            for (int jj = 0; jj < 8; ++jj) {
                const float xv = x[b2 * 8 + jj] * rn;
                const _Float16 hh = (_Float16)xv;
                h[jj] = hh;
                l[jj] = (_Float16)((xv - (float)hh) * 2048.0f);
            }
            qh[tb + (w * 2 + b2) * 16] = h;
            ql[tb + (w * 2 + b2) * 16] = l;
        }
    }
}

// ---- quad-merge 4 sorted 10-lists from LDS (lane<16 active) --------------
__device__ inline void quad_merge_store(
    u64 (*sm)[16][NTOP], int lane, u64* out10)
{
    int p0 = 0, p1 = 0, p2 = 0, p3 = 0;
#pragma unroll
    for (int r = 0; r < NTOP; ++r) {
        const u64 h0 = sm[0][lane][p0], h1 = sm[1][lane][p1];
        const u64 h2 = sm[2][lane][p2], h3 = sm[3][lane][p3];
        u64 m = h0; int sel = 0;
        if (h1 > m) { m = h1; sel = 1; }
        if (h2 > m) { m = h2; sel = 2; }
        if (h3 > m) { m = h3; sel = 3; }
        out10[r] = m;
        p0 += (sel == 0); p1 += (sel == 1); p2 += (sel == 2); p3 += (sel == 3);
    }
}

// ---------------- kernel 2: frame-0 (unmasked), exact per-(q,eighth) ------
__global__ __launch_bounds__(128) void attn_f0(
    const f16x8* __restrict__ kh, const f16x8* __restrict__ kl,
    const f16x8* __restrict__ qh, const f16x8* __restrict__ ql,
    u64* __restrict__ pv)
{
    __shared__ u64 sm[2][4][16][NTOP];

    const int tid  = threadIdx.x;
    const int w    = tid >> 6;
    const int lane = tid & 63;
    const int quad = lane >> 4;
    const int n    = lane & 15;

    const int t   = blockIdx.x * 2 + w;    // qtile 0..63
    const int job = blockIdx.y;            // eighth -> tiles job*8..+8

    const int qb = t * 128 + n;
    const f16x8 bh0 = qh[qb + quad * 16];
    const f16x8 bh1 = qh[qb + (4 + quad) * 16];
    const f16x8 bl0 = ql[qb + quad * 16];
    const f16x8 bl1 = ql[qb + (4 + quad) * 16];

    u64 v[NTOP];
#pragma unroll
    for (int jj = 0; jj < NTOP; ++jj) v[jj] = 0ull;

    const int start = job * 8, end = start + 8;
    const int loff = (n + quad * 16) * 16;
    const char* ph = (const char*)kh + (size_t)start * 2048 + loff;
    const char* pl = (const char*)kl + (size_t)start * 2048 + loff;

    for (int kt = start; kt < end; ++kt) {
        const f16x8 Ah0 = *(const f16x8*)(ph);
        const f16x8 Ah1 = *(const f16x8*)(ph + 1024);
        const f16x8 Al0 = *(const f16x8*)(pl);
        const f16x8 Al1 = *(const f16x8*)(pl + 1024);

        f32x4 accH = {0.f,0.f,0.f,0.f}, accL0 = {0.f,0.f,0.f,0.f}, accL1 = {0.f,0.f,0.f,0.f};
        accH  = __builtin_amdgcn_mfma_f32_16x16x32_f16(Ah0, bh0, accH, 0, 0, 0);
        accH  = __builtin_amdgcn_mfma_f32_16x16x32_f16(Ah1, bh1, accH, 0, 0, 0);
        accL0 = __builtin_amdgcn_mfma_f32_16x16x32_f16(Ah0, bl0, accL0, 0, 0, 0);
        accL0 = __builtin_amdgcn_mfma_f32_16x16x32_f16(Al0, bh0, accL0, 0, 0, 0);
        accL1 = __builtin_amdgcn_mfma_f32_16x16x32_f16(Ah1, bl1, accL1, 0, 0, 0);
        accL1 = __builtin_amdgcn_mfma_f32_16x16x32_f16(Al1, bh1, accL1, 0, 0, 0);

        const int key0 = kt * 16 + quad * 4;
#pragma unroll
        for (int r = 0; r < 4; ++r) {
            const float val = fmaf(accL0[r] + accL1[r], LOSCL, accH[r]);
            const u64 pk = pack_vi(val, key0 + r);
            if (pk > v[NTOP - 1]) ins10(v, pk);
        }
        ph += 2048; pl += 2048;
    }

#pragma unroll
    for (int jj = 0; jj < NTOP; ++jj) sm[w][quad][n][jj] = v[jj];
    __syncthreads();

    if (lane < 16) {
        u64 out10[NTOP];
        quad_merge_store(sm[w], lane, out10);
        const int q = t * 16 + lane;
#pragma unroll
        for (int r = 0; r < NTOP; ++r) pv[(size_t)q * PVLEN + job * NTOP + r] = out10[r];
    }
}

// ---------------- kernel 3: theta = true frame-0 10th (per query) ---------
__global__ __launch_bounds__(256) void theta_refine(
    const u64* __restrict__ pv, float* __restrict__ thmax)
{
    const int q    = blockIdx.x * 4 + (threadIdx.x >> 6);
    const int lane = threadIdx.x & 63;

    u64 l0 = pv[(size_t)q * PVLEN + lane];
    u64 l1 = (lane < 16) ? pv[(size_t)q * PVLEN + 64 + lane] : 0ull;

    u64 m = 0ull;
#pragma unroll
    for (int r = 0; r < NTOP; ++r) {
        u64 c = l0 > l1 ? l0 : l1;
#pragma unroll
        for (int off = 32; off >= 1; off >>= 1) {
            const u32 lo = (u32)c, hi = (u32)(c >> 32);
            const u32 lo2 = (u32)__shfl_xor((int)lo, off);
            const u32 hi2 = (u32)__shfl_xor((int)hi, off);
            const u64 o = ((u64)hi2 << 32) | lo2;
            if (o > c) c = o;
        }
        if (l0 == c) l0 = 0ull;
        if (l1 == c) l1 = 0ull;
        m = c;
    }
    if (lane == 0) thmax[q] = unpack_val(m);
}

// ---------------- kernel 4: masked frames — flat units, LDS-buffered ------
// 1024 blocks x 4 INDEPENDENT waves (no block barrier in hot path). Unit =
// (frame,qy,row): 8 A-loads + 24 MFMA + theta-gated tests. KEY FIX vs R9:
// exceedances append to per-wave LDS lists (ds_atomic: lgkmcnt path — the
// global-load vmcnt queue is NEVER drained inside the unit loop, so loads
// of unit u+1 overlap compute of unit u). Lists flush to global with 32
// concurrent atomicAdds once per qy-change / wave-end (<=2 per wave).
__global__ __launch_bounds__(256, 4) void attn_masked(
    const f16x8* __restrict__ kh, const f16x8* __restrict__ kl,
    const f16x8* __restrict__ qh, const f16x8* __restrict__ ql,
    const float* __restrict__ thmax,
    u64* __restrict__ gcand, int* __restrict__ cnt)
{
    __shared__ u64 wcand[4][32][CAPW];
    __shared__ int wcnt[4][32];

    const int tid  = threadIdx.x;
    const int w    = tid >> 6;
    const int lane = tid & 63;
    const int quad = lane >> 4;
    const int n    = lane & 15;

    if (lane < 32) wcnt[w][lane] = 0;      // wave-private, no sync needed

    const int bidx = ((int)blockIdx.x & 7) * (NBLK / 8) + ((int)blockIdx.x >> 3);
    const int wid  = bidx * 4 + w;          // XCD-contiguous unit chunks
    const int u0   = (int)(((long long)wid * TOTU) >> 12);
    const int u1   = (int)(((long long)(wid + 1) * TOTU) >> 12);

    f16x8 b0h0, b0h1, b0l0, b0l1, b1h0, b1h1, b1l0, b1l1;
    float theta0 = 0.f, theta1 = 0.f;
    int cur_qy = -1, q0 = 0;

    for (int u = u0; u < u1; ++u) {
        // decode u -> (frame, qy, row); wave-uniform
        const int fm1 = u / 604;
        const int rem = u - fm1 * 604;
        int qy, off;
        if (rem < 210) {
            int t = (int)((sqrtf((float)(529 + 8 * rem)) - 23.0f) * 0.5f);
            while ((t * (t + 23)) / 2 > rem) --t;
            while (((t + 1) * (t + 24)) / 2 <= rem) ++t;
            qy = t; off = rem - (t * (t + 23)) / 2;
        } else if (rem < 417) {
            qy = 12 + (rem - 210) / 23; off = (rem - 210) % 23;
        } else {
            const int s = 603 - rem;
            int t = (int)((sqrtf((float)(529 + 8 * s)) - 23.0f) * 0.5f);
            while ((t * (t + 23)) / 2 > s) --t;
            while (((t + 1) * (t + 24)) / 2 <= s) ++t;
            qy = 31 - t;
            off = (12 + t) - 1 - (s - (t * (t + 23)) / 2);
        }
        const int rlo = (qy > 11) ? qy - 11 : 0;
        const int row = rlo + off;
        const int frame = fm1 + 1;

        if (qy != cur_qy) {
            if (cur_qy >= 0) {                 // flush old qy's lists (rare)
                __builtin_amdgcn_wave_barrier();
                if (lane < 32) {
                    const int rc = min(wcnt[w][lane], CAPW);
                    if (rc > 0) {
                        const int qq = cur_qy * 32 + lane;
                        const int base = atomicAdd(&cnt[qq], rc);
                        for (int jf = 0; jf < rc; ++jf) {
                            const int pos = base + jf;
                            if (pos < CAPG) gcand[(size_t)qq * CAPG + pos] = wcand[w][lane][jf];
                        }
                    }
                    wcnt[w][lane] = 0;
                }
                __builtin_amdgcn_wave_barrier();
            }
            cur_qy = qy;
            const int qb = qy * 256 + n;
            b0h0 = qh[qb + quad * 16];       b0h1 = qh[qb + (4 + quad) * 16];
            b0l0 = ql[qb + quad * 16];       b0l1 = ql[qb + (4 + quad) * 16];
            b1h0 = qh[qb + 128 + quad * 16]; b1h1 = qh[qb + 128 + (4 + quad) * 16];
            b1l0 = ql[qb + 128 + quad * 16]; b1l1 = ql[qb + 128 + (4 + quad) * 16];
            q0 = qy * 32 + n;
            theta0 = thmax[q0];
            theta1 = thmax[q0 + 16];
        }

        const int dy    = row - qy;
        const int rem2  = R2 - dy * dy;
        const int tbase = frame * 64 + row * 2;
        const int keyrow = frame * 1024 + row * 32;

#pragma unroll
        for (int kt2 = 0; kt2 < 2; ++kt2) {
            const f16x8* pA = kh + (tbase + kt2) * 128 + n;
            const f16x8* pL = kl + (tbase + kt2) * 128 + n;
            const f16x8 ah0 = pA[quad * 16];
            const f16x8 ah1 = pA[(4 + quad) * 16];
            const f16x8 al0 = pL[quad * 16];
            const f16x8 al1 = pL[(4 + quad) * 16];

            f32x4 H0 = {0.f,0.f,0.f,0.f}, L00 = {0.f,0.f,0.f,0.f}, L01 = {0.f,0.f,0.f,0.f};
            f32x4 H1 = {0.f,0.f,0.f,0.f}, L10 = {0.f,0.f,0.f,0.f}, L11 = {0.f,0.f,0.f,0.f};
            H0  = __builtin_amdgcn_mfma_f32_16x16x32_f16(ah0, b0h0, H0, 0, 0, 0);
            H0  = __builtin_amdgcn_mfma_f32_16x16x32_f16(ah1, b0h1, H0, 0, 0, 0);
            L00 = __builtin_amdgcn_mfma_f32_16x16x32_f16(ah0, b0l0, L00, 0, 0, 0);
            L00 = __builtin_amdgcn_mfma_f32_16x16x32_f16(al0, b0h0, L00, 0, 0, 0);
            L01 = __builtin_amdgcn_mfma_f32_16x16x32_f16(ah1, b0l1, L01, 0, 0, 0);
            L01 = __builtin_amdgcn_mfma_f32_16x16x32_f16(al1, b0h1, L01, 0, 0, 0);
            H1  = __builtin_amdgcn_mfma_f32_16x16x32_f16(ah0, b1h0, H1, 0, 0, 0);
            H1  = __builtin_amdgcn_mfma_f32_16x16x32_f16(ah1, b1h1, H1, 0, 0, 0);
            L10 = __builtin_amdgcn_mfma_f32_16x16x32_f16(ah0, b1l0, L10, 0, 0, 0);
            L10 = __builtin_amdgcn_mfma_f32_16x16x32_f16(al0, b1h0, L10, 0, 0, 0);
            L11 = __builtin_amdgcn_mfma_f32_16x16x32_f16(ah1, b1l1, L11, 0, 0, 0);
            L11 = __builtin_amdgcn_mfma_f32_16x16x32_f16(al1, b1h1, L11, 0, 0, 0);

            const int kx0  = kt2 * 16 + quad * 4;
            const int key0 = keyrow + kx0;
#pragma unroll
            for (int r = 0; r < 4; ++r) {
                const float v0 = fmaf(L00[r] + L01[r], LOSCL, H0[r]);
                const float v1 = fmaf(L10[r] + L11[r], LOSCL, H1[r]);
                if (v0 > theta0) {                        // rare (~0.5%/value)
                    const int dx = kx0 + r - n;
                    if (dx * dx < rem2) {
                        const int pos = atomicAdd(&wcnt[w][n], 1);     // LDS atomic
                        if (pos < CAPW) wcand[w][n][pos] = pack_vi(v0, key0 + r);
                    }
                }
                if (v1 > theta1) {
                    const int dx = kx0 + r - 16 - n;
                    if (dx * dx < rem2) {
                        const int pos = atomicAdd(&wcnt[w][16 + n], 1);
                        if (pos < CAPW) wcand[w][16 + n][pos] = pack_vi(v1, key0 + r);
                    }
                }
            }
        }
    }

    // final flush for the last qy
    __builtin_amdgcn_wave_barrier();
    if (cur_qy >= 0 && lane < 32) {
        const int rc = min(wcnt[w][lane], CAPW);
        if (rc > 0) {
            const int qq = cur_qy * 32 + lane;
            const int base = atomicAdd(&cnt[qq], rc);
            for (int jf = 0; jf < rc; ++jf) {
                const int pos = base + jf;
                if (pos < CAPG) gcand[(size_t)qq * CAPG + pos] = wcand[w][lane][jf];
            }
        }
    }
}

// ---------------- kernel 5: global merge, softmax, gather, write ----------
__global__ __launch_bounds__(64) void finalize_kernel(
    const u64* __restrict__ pv, const u64* __restrict__ gcand,
    const int* __restrict__ cnt, const unsigned short* __restrict__ vt,
    const unsigned short* __restrict__ kin_raw, void* __restrict__ out_)
{
    const int isf  = sniff_fp32(kin_raw);
    const int q    = blockIdx.x;
    const int lane = threadIdx.x;

    u64 lv[8];
    lv[0] = pv[(size_t)q * PVLEN + lane];
    lv[1] = (lane < 16) ? pv[(size_t)q * PVLEN + 64 + lane] : 0ull;
    const int c = min(cnt[q], CAPG);
#pragma unroll
    for (int e = 0; e < 6; ++e) {
        const int idx = e * 64 + lane;
        lv[2 + e] = (idx < c) ? gcand[(size_t)q * CAPG + idx] : 0ull;
    }

    float wv[NTOP]; int wi[NTOP];
#pragma unroll
    for (int r = 0; r < NTOP; ++r) {
        u64 m = lv[0];
#pragma unroll
        for (int e = 1; e < 8; ++e) if (lv[e] > m) m = lv[e];
#pragma unroll
        for (int off = 32; off >= 1; off >>= 1) {
            const u32 lo = (u32)m, hi = (u32)(m >> 32);
            const u32 lo2 = (u32)__shfl_xor((int)lo, off);
            const u32 hi2 = (u32)__shfl_xor((int)hi, off);
            const u64 o = ((u64)hi2 << 32) | lo2;
            if (o > m) m = o;
        }
#pragma unroll
        for (int e = 0; e < 8; ++e) if (lv[e] == m) lv[e] = 0ull;   // consume
        wv[r] = unpack_val(m); wi[r] = unpack_idx(m);
    }

    float ww[NTOP]; float wsum = 0.f;
#pragma unroll
    for (int r = 0; r < NTOP; ++r) { ww[r] = expf((wv[r] - wv[0]) * TSCALE); wsum += ww[r]; }
    const float inv = 1.0f / wsum;

    float acc = 0.f;
#pragma unroll
    for (int r = 0; r < NTOP; ++r)
        acc += ww[r] * bf16bits_to_f32(vt[(size_t)wi[r] * NCH + lane]);
    const float res = acc * inv;

    if (isf) ((float*)out_)[lane * HWQ + q] = res;
    else     ((__hip_bfloat16*)out_)[lane * HWQ + q] = __float2bfloat16(res);
}

// ---------------- launcher ------------------------------------------------
extern "C" void kernel_launch(void* const* d_in, const int* in_sizes, int n_in,
                              void* d_out, int out_size, void* d_ws, size_t ws_size,
                              hipStream_t stream)
{
    const void* qin = d_in[0];   // (64,1024)   bf16 or fp32 (self-sniffed)
    const void* kin = d_in[1];   // (64,40960)
    const void* vin = d_in[2];   // (64,40960)
    // d_in[3] (mask) recomputed on device.

    char* w = (char*)d_ws;
    f16x8*          kh    = (f16x8*)(w);                     //  5,242,880 B
    f16x8*          kl    = (f16x8*)(w + 5242880);           //  5,242,880 B
    f16x8*          qhv   = (f16x8*)(w + 10485760);          //    131,072 B
    f16x8*          qlv   = (f16x8*)(w + 10616832);          //    131,072 B
    unsigned short* vt    = (unsigned short*)(w + 10747904); //  5,242,880 B
    u64*            pv    = (u64*)(w + 15990784);            //    655,360 B
    u64*            gcand = (u64*)(w + 16646144);            //  3,145,728 B
    float*          thmax = (float*)(w + 19791872);          //      4,096 B
    int*            cnt   = (int*)(w + 19795968);            //      4,096 B

    prep_all<<<656, 256, 0, stream>>>(qin, kin, vin, kh, kl, qhv, qlv, vt, cnt);
    attn_f0<<<dim3(32, 8), 128, 0, stream>>>(kh, kl, qhv, qlv, pv);
    theta_refine<<<256, 256, 0, stream>>>(pv, thmax);
    attn_masked<<<NBLK, 256, 0, stream>>>(kh, kl, qhv, qlv, thmax, gcand, cnt);
    finalize_kernel<<<HWQ, 64, 0, stream>>>(pv, gcand, cnt, vt,
                                            (const unsigned short*)kin, d_out);
}